// Round 2
// baseline (642.536 us; speedup 1.0000x reference)
//
#include <hip/hip_runtime.h>
#include <hip/hip_bf16.h>

#define TOKENS 8192
#define IN_F   4096
#define OUT_F  4096

#define BM 256
#define BN 256
#define BK 64
#define NT (IN_F / BK)   // 64 K-tiles

typedef __attribute__((ext_vector_type(8))) short bf16x8;    // 8 bf16 = 4 VGPRs
typedef __attribute__((ext_vector_type(16))) float f32x16;   // 32x32 MFMA acc

static __device__ __forceinline__ unsigned short f2bf(float f) {
    union { float f; unsigned int u; } v;
    v.f = f;
    unsigned int r = v.u + 0x7fffu + ((v.u >> 16) & 1u);   // RNE
    return (unsigned short)(r >> 16);
}

// rho ~ N(-4.6,1): exp(rho) ~ 0.01, fast log/exp error ~1e-6 rel << bf16 quantization
static __device__ __forceinline__ float softplus_fast(float x) {
    return __logf(1.0f + __expf(x));
}

#define XBLK 32768   // (TOKENS*IN_F/4)/256
#define WBLK 16384   // (OUT_F*IN_F/4)/256

// ---- fused prep: x->bf16, W = mu + softplus(rho)*eps -> bf16, bias fp32
__global__ __launch_bounds__(256) void prep_all_kernel(
        const float* __restrict__ x,
        const float* __restrict__ wmu,  const float* __restrict__ wrho,
        const float* __restrict__ epsw,
        const float* __restrict__ bmu,  const float* __restrict__ brho,
        const float* __restrict__ bepsb,
        __hip_bfloat16* __restrict__ xb, __hip_bfloat16* __restrict__ wb,
        float* __restrict__ bias) {
    const int b = blockIdx.x, t = threadIdx.x;
    if (b < XBLK) {
        const int i = b * 256 + t;
        float4 v = ((const float4*)x)[i];
        ushort4 o;
        o.x = f2bf(v.x); o.y = f2bf(v.y); o.z = f2bf(v.z); o.w = f2bf(v.w);
        ((ushort4*)xb)[i] = o;
    } else if (b < XBLK + WBLK) {
        const int i = (b - XBLK) * 256 + t;
        float4 m4 = ((const float4*)wmu)[i];
        float4 r4 = ((const float4*)wrho)[i];
        float4 e4 = ((const float4*)epsw)[i];
        ushort4 o;
        o.x = f2bf(m4.x + softplus_fast(r4.x) * e4.x);
        o.y = f2bf(m4.y + softplus_fast(r4.y) * e4.y);
        o.z = f2bf(m4.z + softplus_fast(r4.z) * e4.z);
        o.w = f2bf(m4.w + softplus_fast(r4.w) * e4.w);
        ((ushort4*)wb)[i] = o;
    } else {
        const int i = (b - XBLK - WBLK) * 256 + t;   // 0..1023
        float4 m4 = ((const float4*)bmu)[i];
        float4 r4 = ((const float4*)brho)[i];
        float4 e4 = ((const float4*)bepsb)[i];
        float4 o;
        o.x = m4.x + softplus_fast(r4.x) * e4.x;
        o.y = m4.y + softplus_fast(r4.y) * e4.y;
        o.z = m4.z + softplus_fast(r4.z) * e4.z;
        o.w = m4.w + softplus_fast(r4.w) * e4.w;
        ((float4*)bias)[i] = o;
    }
}

// ---- 256x256 tile, BK=64, 8 waves (2M x 4N), 4 phases/K-tile, counted vmcnt(6).
// MFMA: 32x32x16 bf16 (2495 TF pipe vs 2176 for 16x16). Per wave: 4m x 2n f32x16 accs.
// Operand layout: lane l holds row (l&31), k=(l>>5)*8+e. C/D: col=lane&31,
// row=(reg&3)+8*(reg>>2)+4*(lane>>5)  [m74/m101].
// LDS: [2 slots][2 K-halves][256 rows][32 cols] bf16 per operand = 128 KiB total.
// Swizzle (both-sides, rule #21): source chunk ^= (row>>1)&3 at staging (linear LDS
// dest for global_load_lds); reads use chunk = kc ^ ((rl>>1)&3). Conflict-free within
// every 8-lane b128 batch (verified 0 conflicts in R1 with the same involution).
// Schedule per K-tile t:
//   P0: read A[mt0-1]+B kh0 | stage Bkh0(t+1) | bar | lgkm0 | 8 MFMA | bar
//   P1: read A[mt2-3] kh0   | stage Akh1(t+1) | bar | lgkm0 | 8 MFMA | vmcnt(6) bar
//   P2: read A[mt0-1]+B kh1 | stage Bkh1(t+1) | bar | lgkm0 | 8 MFMA | bar
//   P3: read A[mt2-3] kh1   | stage Akh0(t+2) | bar | lgkm0 | 8 MFMA | vmcnt(6) bar
// vmcnt(6) leaves 3 half-tiles (6 loads) in flight; oldest 4 loads (the halves the
// next two phases read) are guaranteed landed.
__global__ __launch_bounds__(512, 2) void gemm_256_kernel(
        const __hip_bfloat16* __restrict__ Xb,   // [TOKENS, IN_F]
        const __hip_bfloat16* __restrict__ Wb,   // [OUT_F, IN_F]
        const float* __restrict__ bias,          // [OUT_F]
        float* __restrict__ C) {                 // [TOKENS, OUT_F]
    __shared__ __align__(16) __hip_bfloat16 ldsA[2][2][BM * 32];
    __shared__ __align__(16) __hip_bfloat16 ldsB[2][2][BN * 32];

    const int tid  = threadIdx.x;
    const int lane = tid & 63;
    const int wave = tid >> 6;
    const int wm   = wave >> 2;   // 0..1 : wave's 128-row block
    const int wn   = wave & 3;    // 0..3 : wave's 64-col block
    const int rl   = lane & 31;
    const int h    = lane >> 5;
    const int xsw  = (rl >> 1) & 3;

    // XCD-aware bijective swizzle: nwg = 512 = 8*64
    int bid = blockIdx.y * 16 + blockIdx.x;
    bid = (bid & 7) * 64 + (bid >> 3);
    const int colBase = (bid & 15) * BN;   // out-feature dim (16 col-tiles)
    const int rowBase = (bid >> 4) * BM;   // token dim (32 row-tiles)

    // staging: thread t -> row t/4, 16B chunk (t&3), source pre-swizzled
    const int sRow = tid >> 2;
    const int sCol = ((tid & 3) ^ ((tid >> 3) & 3)) * 8;   // chunk ^ ((row>>1)&3)
    const __hip_bfloat16* gA = Xb + (size_t)(rowBase + sRow) * IN_F + sCol;
    const __hip_bfloat16* gB = Wb + (size_t)(colBase + sRow) * IN_F + sCol;
    const int dstE = tid * 8;   // linear LDS dest (elems)

    auto stageA = [&](int slot, int kh, int kt) {
        const __hip_bfloat16* src = gA + (size_t)kt * BK + (size_t)kh * 32;
        __hip_bfloat16* dst = &ldsA[slot][kh][dstE];
        __builtin_amdgcn_global_load_lds(
            (const __attribute__((address_space(1))) void*)src,
            (__attribute__((address_space(3))) void*)dst, 16, 0, 0);
        __builtin_amdgcn_global_load_lds(
            (const __attribute__((address_space(1))) void*)(src + (size_t)128 * IN_F),
            (__attribute__((address_space(3))) void*)(dst + 4096), 16, 0, 0);
    };
    auto stageB = [&](int slot, int kh, int kt) {
        const __hip_bfloat16* src = gB + (size_t)kt * BK + (size_t)kh * 32;
        __hip_bfloat16* dst = &ldsB[slot][kh][dstE];
        __builtin_amdgcn_global_load_lds(
            (const __attribute__((address_space(1))) void*)src,
            (__attribute__((address_space(3))) void*)dst, 16, 0, 0);
        __builtin_amdgcn_global_load_lds(
            (const __attribute__((address_space(1))) void*)(src + (size_t)128 * IN_F),
            (__attribute__((address_space(3))) void*)(dst + 4096), 16, 0, 0);
    };

    f32x16 acc[4][2];
#pragma unroll
    for (int m = 0; m < 4; ++m)
#pragma unroll
        for (int n = 0; n < 2; ++n)
#pragma unroll
            for (int r = 0; r < 16; ++r) acc[m][n][r] = 0.f;

    // per-lane read offsets (elements) within a [256][32] kh-buffer
    const int aBase = (wm * 128 + rl) * 32;
    const int bBase = (wn * 64 + rl) * 32;
    const int c0 = ((0 + h) ^ xsw) * 8;   // k-slice s=0
    const int c1 = ((2 + h) ^ xsw) * 8;   // k-slice s=1

    // prologue: 5 half-tiles in flight; wait for tile0 kh0 (A,B)
    stageA(0, 0, 0);
    stageB(0, 0, 0);
    stageA(0, 1, 0);
    stageB(0, 1, 0);
    stageA(1, 0, 1);
    asm volatile("s_waitcnt vmcnt(6)" ::: "memory");
    __builtin_amdgcn_s_barrier();

    bf16x8 aR[2][2], bR[2][2];

    for (int t = 0; t < NT; ++t) {
        const int cs = t & 1, ns = cs ^ 1;
        const int t1 = (t + 1 < NT) ? (t + 1) : (NT - 1);   // clamp keeps vmcnt uniform
        const int t2 = (t + 2 < NT) ? (t + 2) : (NT - 1);
        const __hip_bfloat16* A0 = &ldsA[cs][0][0];
        const __hip_bfloat16* A1 = &ldsA[cs][1][0];
        const __hip_bfloat16* B0 = &ldsB[cs][0][0];
        const __hip_bfloat16* B1 = &ldsB[cs][1][0];

        // ---------- P0: (mt0-1)x(nt0-1), kh0
        aR[0][0] = *(const bf16x8*)(A0 + aBase + c0);
        aR[0][1] = *(const bf16x8*)(A0 + aBase + c1);
        aR[1][0] = *(const bf16x8*)(A0 + aBase + 1024 + c0);
        aR[1][1] = *(const bf16x8*)(A0 + aBase + 1024 + c1);
        bR[0][0] = *(const bf16x8*)(B0 + bBase + c0);
        bR[0][1] = *(const bf16x8*)(B0 + bBase + c1);
        bR[1][0] = *(const bf16x8*)(B0 + bBase + 1024 + c0);
        bR[1][1] = *(const bf16x8*)(B0 + bBase + 1024 + c1);
        stageB(ns, 0, t1);
        __builtin_amdgcn_s_barrier();
        asm volatile("s_waitcnt lgkmcnt(0)" ::: "memory");
        __builtin_amdgcn_s_setprio(1);
#pragma unroll
        for (int s = 0; s < 2; ++s)
#pragma unroll
            for (int mt = 0; mt < 2; ++mt)
#pragma unroll
                for (int nt = 0; nt < 2; ++nt)
                    acc[mt][nt] = __builtin_amdgcn_mfma_f32_32x32x16_bf16(
                        aR[mt][s], bR[nt][s], acc[mt][nt], 0, 0, 0);
        __builtin_amdgcn_s_setprio(0);
        __builtin_amdgcn_s_barrier();

        // ---------- P1: (mt2-3)x(nt0-1), kh0 (reuse bR)
        aR[0][0] = *(const bf16x8*)(A0 + aBase + 2048 + c0);
        aR[0][1] = *(const bf16x8*)(A0 + aBase + 2048 + c1);
        aR[1][0] = *(const bf16x8*)(A0 + aBase + 3072 + c0);
        aR[1][1] = *(const bf16x8*)(A0 + aBase + 3072 + c1);
        stageA(ns, 1, t1);
        __builtin_amdgcn_s_barrier();
        asm volatile("s_waitcnt lgkmcnt(0)" ::: "memory");
        __builtin_amdgcn_s_setprio(1);
#pragma unroll
        for (int s = 0; s < 2; ++s)
#pragma unroll
            for (int mt = 0; mt < 2; ++mt)
#pragma unroll
                for (int nt = 0; nt < 2; ++nt)
                    acc[mt + 2][nt] = __builtin_amdgcn_mfma_f32_32x32x16_bf16(
                        aR[mt][s], bR[nt][s], acc[mt + 2][nt], 0, 0, 0);
        __builtin_amdgcn_s_setprio(0);
        asm volatile("s_waitcnt vmcnt(6)" ::: "memory");   // Akh1(t),Bkh1(t) landed
        __builtin_amdgcn_s_barrier();

        // ---------- P2: (mt0-1)x(nt0-1), kh1
        aR[0][0] = *(const bf16x8*)(A1 + aBase + c0);
        aR[0][1] = *(const bf16x8*)(A1 + aBase + c1);
        aR[1][0] = *(const bf16x8*)(A1 + aBase + 1024 + c0);
        aR[1][1] = *(const bf16x8*)(A1 + aBase + 1024 + c1);
        bR[0][0] = *(const bf16x8*)(B1 + bBase + c0);
        bR[0][1] = *(const bf16x8*)(B1 + bBase + c1);
        bR[1][0] = *(const bf16x8*)(B1 + bBase + 1024 + c0);
        bR[1][1] = *(const bf16x8*)(B1 + bBase + 1024 + c1);
        stageB(ns, 1, t1);
        __builtin_amdgcn_s_barrier();
        asm volatile("s_waitcnt lgkmcnt(0)" ::: "memory");
        __builtin_amdgcn_s_setprio(1);
#pragma unroll
        for (int s = 0; s < 2; ++s)
#pragma unroll
            for (int mt = 0; mt < 2; ++mt)
#pragma unroll
                for (int nt = 0; nt < 2; ++nt)
                    acc[mt][nt] = __builtin_amdgcn_mfma_f32_32x32x16_bf16(
                        aR[mt][s], bR[nt][s], acc[mt][nt], 0, 0, 0);
        __builtin_amdgcn_s_setprio(0);
        __builtin_amdgcn_s_barrier();

        // ---------- P3: (mt2-3)x(nt0-1), kh1 (reuse bR); stage Akh0(t+2)
        aR[0][0] = *(const bf16x8*)(A1 + aBase + 2048 + c0);
        aR[0][1] = *(const bf16x8*)(A1 + aBase + 2048 + c1);
        aR[1][0] = *(const bf16x8*)(A1 + aBase + 3072 + c0);
        aR[1][1] = *(const bf16x8*)(A1 + aBase + 3072 + c1);
        stageA(cs, 0, t2);
        __builtin_amdgcn_s_barrier();
        asm volatile("s_waitcnt lgkmcnt(0)" ::: "memory");
        __builtin_amdgcn_s_setprio(1);
#pragma unroll
        for (int s = 0; s < 2; ++s)
#pragma unroll
            for (int mt = 0; mt < 2; ++mt)
#pragma unroll
                for (int nt = 0; nt < 2; ++nt)
                    acc[mt + 2][nt] = __builtin_amdgcn_mfma_f32_32x32x16_bf16(
                        aR[mt][s], bR[nt][s], acc[mt + 2][nt], 0, 0, 0);
        __builtin_amdgcn_s_setprio(0);
        asm volatile("s_waitcnt vmcnt(6)" ::: "memory");   // Akh0(t+1),Bkh0(t+1) landed
        __builtin_amdgcn_s_barrier();
    }

    // epilogue: 32x32 C/D layout col=lane&31, row=(reg&3)+8*(reg>>2)+4*h
#pragma unroll
    for (int nt = 0; nt < 2; ++nt) {
        const int col = colBase + wn * 64 + nt * 32 + rl;
        const float bv = bias[col];
#pragma unroll
        for (int mt = 0; mt < 4; ++mt) {
            const int row0 = rowBase + wm * 128 + mt * 32 + h * 4;
#pragma unroll
            for (int r = 0; r < 16; ++r) {
                const int row = row0 + (r & 3) + 8 * (r >> 2);
                C[(size_t)row * OUT_F + col] = acc[mt][nt][r] + bv;
            }
        }
    }
}

extern "C" void kernel_launch(void* const* d_in, const int* in_sizes, int n_in,
                              void* d_out, int out_size, void* d_ws, size_t ws_size,
                              hipStream_t stream) {
    const float* x    = (const float*)d_in[0];
    const float* wmu  = (const float*)d_in[1];
    const float* wrho = (const float*)d_in[2];
    const float* bmu  = (const float*)d_in[3];
    const float* brho = (const float*)d_in[4];
    const float* epsw = (const float*)d_in[5];
    const float* epsb = (const float*)d_in[6];
    float* out = (float*)d_out;

    // workspace: x_bf16 (67108864 B) | w_bf16 (33554432 B) | bias (16384 B)
    char* ws = (char*)d_ws;
    __hip_bfloat16* xb = (__hip_bfloat16*)ws;
    __hip_bfloat16* wb = (__hip_bfloat16*)(ws + (size_t)TOKENS * IN_F * 2);
    float* bias = (float*)(ws + (size_t)TOKENS * IN_F * 2 + (size_t)OUT_F * IN_F * 2);

    prep_all_kernel<<<XBLK + WBLK + 4, 256, 0, stream>>>(
        x, wmu, wrho, epsw, bmu, brho, epsb, xb, wb, bias);

    dim3 grid(OUT_F / BN, TOKENS / BM);   // (16, 32)
    gemm_256_kernel<<<grid, 512, 0, stream>>>(xb, wb, bias, out);
}

// Round 3
// 607.930 us; speedup vs baseline: 1.0569x; 1.0569x over previous
//
#include <hip/hip_runtime.h>
#include <hip/hip_bf16.h>

#define TOKENS 8192
#define IN_F   4096
#define OUT_F  4096

#define BM 256
#define BN 256
#define BK 64
#define NT (IN_F / BK)   // 64 K-tiles

typedef __attribute__((ext_vector_type(8))) short bf16x8;   // 8 bf16 = 4 VGPRs
typedef __attribute__((ext_vector_type(4))) float f32x4;

static __device__ __forceinline__ unsigned short f2bf(float f) {
    union { float f; unsigned int u; } v;
    v.f = f;
    unsigned int r = v.u + 0x7fffu + ((v.u >> 16) & 1u);   // RNE
    return (unsigned short)(r >> 16);
}

// rho ~ N(-4.6,1): exp(rho) ~ 0.01, fast log/exp error ~1e-6 rel << bf16 quantization
static __device__ __forceinline__ float softplus_fast(float x) {
    return __logf(1.0f + __expf(x));
}

#define XBLK 32768   // (TOKENS*IN_F/4)/256
#define WBLK 16384   // (OUT_F*IN_F/4)/256

// ---- fused prep: x->bf16, W = mu + softplus(rho)*eps -> bf16, bias fp32
__global__ __launch_bounds__(256) void prep_all_kernel(
        const float* __restrict__ x,
        const float* __restrict__ wmu,  const float* __restrict__ wrho,
        const float* __restrict__ epsw,
        const float* __restrict__ bmu,  const float* __restrict__ brho,
        const float* __restrict__ bepsb,
        __hip_bfloat16* __restrict__ xb, __hip_bfloat16* __restrict__ wb,
        float* __restrict__ bias) {
    const int b = blockIdx.x, t = threadIdx.x;
    if (b < XBLK) {
        const int i = b * 256 + t;
        float4 v = ((const float4*)x)[i];
        ushort4 o;
        o.x = f2bf(v.x); o.y = f2bf(v.y); o.z = f2bf(v.z); o.w = f2bf(v.w);
        ((ushort4*)xb)[i] = o;
    } else if (b < XBLK + WBLK) {
        const int i = (b - XBLK) * 256 + t;
        float4 m4 = ((const float4*)wmu)[i];
        float4 r4 = ((const float4*)wrho)[i];
        float4 e4 = ((const float4*)epsw)[i];
        ushort4 o;
        o.x = f2bf(m4.x + softplus_fast(r4.x) * e4.x);
        o.y = f2bf(m4.y + softplus_fast(r4.y) * e4.y);
        o.z = f2bf(m4.z + softplus_fast(r4.z) * e4.z);
        o.w = f2bf(m4.w + softplus_fast(r4.w) * e4.w);
        ((ushort4*)wb)[i] = o;
    } else {
        const int i = (b - XBLK - WBLK) * 256 + t;   // 0..1023
        float4 m4 = ((const float4*)bmu)[i];
        float4 r4 = ((const float4*)brho)[i];
        float4 e4 = ((const float4*)bepsb)[i];
        float4 o;
        o.x = m4.x + softplus_fast(r4.x) * e4.x;
        o.y = m4.y + softplus_fast(r4.y) * e4.y;
        o.z = m4.z + softplus_fast(r4.z) * e4.z;
        o.w = m4.w + softplus_fast(r4.w) * e4.w;
        ((float4*)bias)[i] = o;
    }
}

// ---- 256x256 tile, BK=64, 8 waves (2M x 4N), 16x16x32 MFMA, 4 phases/K-tile,
// counted vmcnt(6), K-loop unrolled x2 so LDS slot indices are compile-time consts
// (kills per-iter pointer-select VALU; all ds_read addrs = one VGPR + immediate).
// LDS: [2 slots][2 K-halves][256 rows][32 cols] bf16 per operand = 128 KiB.
// Swizzle (rule #21, both sides): staging source chunk ^= (row>>1)&3, linear LDS dest;
// read side chunk = quad ^ ((fr>>1)&3). Empirically 0 bank conflicts (R1).
// Schedule per K-tile t:
//   P0: read A[m0-3]kh0 + B kh0 | stage Bkh0(t+1) | bar | lgkm0 | 16 MFMA | bar
//   P1: read A[m4-7]kh0         | stage Akh1(t+1) | bar | lgkm0 | 16 MFMA | vmcnt(6) bar
//   P2: read A[m0-3]kh1 + B kh1 | stage Bkh1(t+1) | bar | lgkm0 | 16 MFMA | bar
//   P3: read A[m4-7]kh1         | stage Akh0(t+2) | bar | lgkm0 | 16 MFMA | vmcnt(6) bar
// vmcnt(6) leaves 3 half-tiles (6 loads) in flight; the halves the next two phases
// read are guaranteed landed.
__global__ __launch_bounds__(512, 2) void gemm_256_kernel(
        const __hip_bfloat16* __restrict__ Xb,   // [TOKENS, IN_F]
        const __hip_bfloat16* __restrict__ Wb,   // [OUT_F, IN_F]
        const float* __restrict__ bias,          // [OUT_F]
        float* __restrict__ C) {                 // [TOKENS, OUT_F]
    __shared__ __align__(16) __hip_bfloat16 ldsA[2][2][BM * 32];
    __shared__ __align__(16) __hip_bfloat16 ldsB[2][2][BN * 32];

    const int tid  = threadIdx.x;
    const int lane = tid & 63;
    const int wave = tid >> 6;
    const int wm   = wave >> 2;   // 0..1 : wave's 128-row block
    const int wn   = wave & 3;    // 0..3 : wave's 64-col block
    const int fr   = lane & 15;
    const int quad = lane >> 4;

    const int rowBase = blockIdx.y * BM;   // token dim
    const int colBase = blockIdx.x * BN;   // out-feature dim

    // staging: thread t -> row t/4, 16B chunk (t&3), source pre-swizzled
    const int sRow = tid >> 2;
    const int sCol = ((tid & 3) ^ ((tid >> 3) & 3)) * 8;   // chunk ^ ((row>>1)&3)
    const __hip_bfloat16* gA = Xb + (size_t)(rowBase + sRow) * IN_F + sCol;
    const __hip_bfloat16* gB = Wb + (size_t)(colBase + sRow) * IN_F + sCol;
    const int dstE = tid * 8;   // linear LDS dest (elems)

    auto stageA = [&](int slot, int kh, int kt) {
        const __hip_bfloat16* src = gA + (size_t)kt * BK + (size_t)kh * 32;
        __hip_bfloat16* dst = &ldsA[slot][kh][dstE];
        __builtin_amdgcn_global_load_lds(
            (const __attribute__((address_space(1))) void*)src,
            (__attribute__((address_space(3))) void*)dst, 16, 0, 0);
        __builtin_amdgcn_global_load_lds(
            (const __attribute__((address_space(1))) void*)(src + (size_t)128 * IN_F),
            (__attribute__((address_space(3))) void*)(dst + 4096), 16, 0, 0);
    };
    auto stageB = [&](int slot, int kh, int kt) {
        const __hip_bfloat16* src = gB + (size_t)kt * BK + (size_t)kh * 32;
        __hip_bfloat16* dst = &ldsB[slot][kh][dstE];
        __builtin_amdgcn_global_load_lds(
            (const __attribute__((address_space(1))) void*)src,
            (__attribute__((address_space(3))) void*)dst, 16, 0, 0);
        __builtin_amdgcn_global_load_lds(
            (const __attribute__((address_space(1))) void*)(src + (size_t)128 * IN_F),
            (__attribute__((address_space(3))) void*)(dst + 4096), 16, 0, 0);
    };

    f32x4 acc[8][4];
#pragma unroll
    for (int m = 0; m < 8; ++m)
#pragma unroll
        for (int n = 0; n < 4; ++n) acc[m][n] = (f32x4){0.f, 0.f, 0.f, 0.f};

    // per-lane read offset (elements) within a [256][32] kh-buffer
    const int aOffE = wm * 4096 + fr * 32 + (quad ^ ((fr >> 1) & 3)) * 8;
    const int bOffE = wn * 2048 + fr * 32 + (quad ^ ((fr >> 1) & 3)) * 8;

    // prologue: 5 half-tiles in flight; wait for tile0 kh0 (A,B)
    stageA(0, 0, 0);
    stageB(0, 0, 0);
    stageA(0, 1, 0);
    stageB(0, 1, 0);
    stageA(1, 0, 1);
    asm volatile("s_waitcnt vmcnt(6)" ::: "memory");
    __builtin_amdgcn_s_barrier();

    bf16x8 aR[4], bR[4];

    // K-tile body: CS/NS are literal constants per unrolled copy.
#define KTILE(CS, NS, T1, T2)                                                      \
    {                                                                              \
        const __hip_bfloat16* A0 = &ldsA[CS][0][0];                                \
        const __hip_bfloat16* A1 = &ldsA[CS][1][0];                                \
        const __hip_bfloat16* B0 = &ldsB[CS][0][0];                                \
        const __hip_bfloat16* B1 = &ldsB[CS][1][0];                                \
        /* P0 */                                                                   \
        _Pragma("unroll")                                                          \
        for (int m = 0; m < 4; ++m) aR[m] = *(const bf16x8*)(A0 + aOffE + m * 512);\
        _Pragma("unroll")                                                          \
        for (int n = 0; n < 4; ++n) bR[n] = *(const bf16x8*)(B0 + bOffE + n * 512);\
        stageB(NS, 0, T1);                                                         \
        __builtin_amdgcn_s_barrier();                                              \
        asm volatile("s_waitcnt lgkmcnt(0)" ::: "memory");                         \
        __builtin_amdgcn_s_setprio(1);                                             \
        _Pragma("unroll")                                                          \
        for (int n = 0; n < 4; ++n)                                                \
            _Pragma("unroll")                                                      \
            for (int m = 0; m < 4; ++m)                                            \
                acc[m][n] = __builtin_amdgcn_mfma_f32_16x16x32_bf16(               \
                    aR[m], bR[n], acc[m][n], 0, 0, 0);                             \
        __builtin_amdgcn_s_setprio(0);                                             \
        __builtin_amdgcn_s_barrier();                                              \
        /* P1 */                                                                   \
        _Pragma("unroll")                                                          \
        for (int m = 0; m < 4; ++m)                                                \
            aR[m] = *(const bf16x8*)(A0 + aOffE + (m + 4) * 512);                  \
        stageA(NS, 1, T1);                                                         \
        __builtin_amdgcn_s_barrier();                                              \
        asm volatile("s_waitcnt lgkmcnt(0)" ::: "memory");                         \
        __builtin_amdgcn_s_setprio(1);                                             \
        _Pragma("unroll")                                                          \
        for (int n = 0; n < 4; ++n)                                                \
            _Pragma("unroll")                                                      \
            for (int m = 0; m < 4; ++m)                                            \
                acc[m + 4][n] = __builtin_amdgcn_mfma_f32_16x16x32_bf16(           \
                    aR[m], bR[n], acc[m + 4][n], 0, 0, 0);                         \
        __builtin_amdgcn_s_setprio(0);                                             \
        asm volatile("s_waitcnt vmcnt(6)" ::: "memory");                           \
        __builtin_amdgcn_s_barrier();                                              \
        /* P2 */                                                                   \
        _Pragma("unroll")                                                          \
        for (int m = 0; m < 4; ++m) aR[m] = *(const bf16x8*)(A1 + aOffE + m * 512);\
        _Pragma("unroll")                                                          \
        for (int n = 0; n < 4; ++n) bR[n] = *(const bf16x8*)(B1 + bOffE + n * 512);\
        stageB(NS, 1, T1);                                                         \
        __builtin_amdgcn_s_barrier();                                              \
        asm volatile("s_waitcnt lgkmcnt(0)" ::: "memory");                         \
        __builtin_amdgcn_s_setprio(1);                                             \
        _Pragma("unroll")                                                          \
        for (int n = 0; n < 4; ++n)                                                \
            _Pragma("unroll")                                                      \
            for (int m = 0; m < 4; ++m)                                            \
                acc[m][n] = __builtin_amdgcn_mfma_f32_16x16x32_bf16(               \
                    aR[m], bR[n], acc[m][n], 0, 0, 0);                             \
        __builtin_amdgcn_s_setprio(0);                                             \
        __builtin_amdgcn_s_barrier();                                              \
        /* P3 */                                                                   \
        _Pragma("unroll")                                                          \
        for (int m = 0; m < 4; ++m)                                                \
            aR[m] = *(const bf16x8*)(A1 + aOffE + (m + 4) * 512);                  \
        stageA(CS, 0, T2);                                                         \
        __builtin_amdgcn_s_barrier();                                              \
        asm volatile("s_waitcnt lgkmcnt(0)" ::: "memory");                         \
        __builtin_amdgcn_s_setprio(1);                                             \
        _Pragma("unroll")                                                          \
        for (int n = 0; n < 4; ++n)                                                \
            _Pragma("unroll")                                                      \
            for (int m = 0; m < 4; ++m)                                            \
                acc[m + 4][n] = __builtin_amdgcn_mfma_f32_16x16x32_bf16(           \
                    aR[m], bR[n], acc[m + 4][n], 0, 0, 0);                         \
        __builtin_amdgcn_s_setprio(0);                                             \
        asm volatile("s_waitcnt vmcnt(6)" ::: "memory");                           \
        __builtin_amdgcn_s_barrier();                                              \
    }

    for (int tt = 0; tt < NT; tt += 2) {
        const int e1 = (tt + 1 < NT) ? (tt + 1) : (NT - 1);   // clamps keep vmcnt uniform
        const int e2 = (tt + 2 < NT) ? (tt + 2) : (NT - 1);
        const int e3 = (tt + 3 < NT) ? (tt + 3) : (NT - 1);
        KTILE(0, 1, e1, e2)          // even tile: slot 0, prefetch into slot 1
        KTILE(1, 0, e2, e3)          // odd  tile: slot 1, prefetch into slot 0
    }
#undef KTILE

    // epilogue: C/D layout col=lane&15, row=quad*4+reg
#pragma unroll
    for (int nt = 0; nt < 4; ++nt) {
        const int col = colBase + wn * 64 + nt * 16 + fr;
        const float bv = bias[col];
#pragma unroll
        for (int mt = 0; mt < 8; ++mt) {
            const int row = rowBase + wm * 128 + mt * 16 + quad * 4;
#pragma unroll
            for (int r = 0; r < 4; ++r)
                C[(size_t)(row + r) * OUT_F + col] = acc[mt][nt][r] + bv;
        }
    }
}

extern "C" void kernel_launch(void* const* d_in, const int* in_sizes, int n_in,
                              void* d_out, int out_size, void* d_ws, size_t ws_size,
                              hipStream_t stream) {
    const float* x    = (const float*)d_in[0];
    const float* wmu  = (const float*)d_in[1];
    const float* wrho = (const float*)d_in[2];
    const float* bmu  = (const float*)d_in[3];
    const float* brho = (const float*)d_in[4];
    const float* epsw = (const float*)d_in[5];
    const float* epsb = (const float*)d_in[6];
    float* out = (float*)d_out;

    // workspace: x_bf16 (67108864 B) | w_bf16 (33554432 B) | bias (16384 B)
    char* ws = (char*)d_ws;
    __hip_bfloat16* xb = (__hip_bfloat16*)ws;
    __hip_bfloat16* wb = (__hip_bfloat16*)(ws + (size_t)TOKENS * IN_F * 2);
    float* bias = (float*)(ws + (size_t)TOKENS * IN_F * 2 + (size_t)OUT_F * IN_F * 2);

    prep_all_kernel<<<XBLK + WBLK + 4, 256, 0, stream>>>(
        x, wmu, wrho, epsw, bmu, brho, epsb, xb, wb, bias);

    dim3 grid(OUT_F / BN, TOKENS / BM);   // (16, 32)
    gemm_256_kernel<<<grid, 512, 0, stream>>>(xb, wb, bias, out);
}